// Round 7
// baseline (142.584 us; speedup 1.0000x reference)
//
#include <hip/hip_runtime.h>
#include <hip/hip_bf16.h>

// N=32 time, 32x32 grid, C=64 (H=4 x D=16), 3x3x3 offsets (M=27), 2 layers.
// R18 = R17 (no-m-split, 27-iter wave loop, softmax in regs) + occupancy:
//  - BiasS dropped; k/v biases load as global float4 per m (27KB total, L1-
//    resident across 12 waves). LDS 56.4 -> 42.5 KB => 3 blocks/CU (was 2),
//    3 waves/SIMD (+50% latency hiding for the m-body dependency chains).
//  - __launch_bounds__(256,3): 170-VGPR budget, est. live ~150. Spill
//    tripwire = WRITE_SIZE >> 4MB (R12 lesson).

typedef short short8_t __attribute__((ext_vector_type(8)));
typedef float floatx16 __attribute__((ext_vector_type(16)));

__device__ __forceinline__ short f2bs(float f) {
    __hip_bfloat16 h = __float2bfloat16(f);
    return *reinterpret_cast<short*>(&h);
}
__device__ __forceinline__ float bs2f(short s) {
    union { unsigned u; float f; } v;
    v.u = ((unsigned)(unsigned short)s) << 16;
    return v.f;
}
// swizzled halo addressing: rowid in [0,324), 8 chunks of 8 shorts, pitch 64
__device__ __forceinline__ int hn_idx(int rowid, int chunk) {
    return rowid * 64 + ((chunk ^ (rowid & 7)) << 3);
}
// p(lane) + p(lane^32), all lanes (VALU pipe, no DS)
__device__ __forceinline__ float half_sum(float p) {
    float a = p, b = p;
    asm("v_permlane32_swap_b32 %0, %1" : "+v"(a), "+v"(b));
    return a + b;
}

// ---------------- prep: repack weights (coalesced) + BN partial sums ----------------
// blocks 0..109: one matrix each. 110..141: BN partial sums.
__global__ void prep_kernel(const float* __restrict__ Wq, const float* __restrict__ Wk,
                            const float* __restrict__ Wv, short* __restrict__ dst,
                            const float* __restrict__ x, float* __restrict__ sums) {
    if (blockIdx.x < 110) {
        __shared__ float Wf[4096];
        const int mat = blockIdx.x;
        const float* W;
        if (mat < 2)       W = Wq + mat * 4096;
        else if (mat < 56) W = Wk + (mat - 2) * 4096;
        else               W = Wv + (mat - 56) * 4096;
        const float4* W4 = (const float4*)W;
        #pragma unroll
        for (int i = 0; i < 4; ++i) {
            const int idx = threadIdx.x + i * 256;
            *(float4*)&Wf[idx * 4] = W4[idx];
        }
        __syncthreads();
        // out entry t2 = (hp*4+kk)*64 + lane; A[row=hp*32+(lane&31)][k] layout
        #pragma unroll
        for (int u = 0; u < 2; ++u) {
            const int t2 = u * 256 + threadIdx.x;
            const int hp = t2 >> 8, kk = (t2 >> 6) & 3, lane = t2 & 63;
            const int krow = kk * 16 + ((lane >> 5) << 3);
            const int col  = hp * 32 + (lane & 31);
            short8_t v;
            #pragma unroll
            for (int j = 0; j < 8; ++j) v[j] = f2bs(Wf[(krow + j) * 64 + col]);
            *(short8_t*)&dst[(size_t)mat * 4096 + t2 * 8] = v;
        }
    } else {
        int bid = blockIdx.x - 110;
        int t = bid * 256 + threadIdx.x;          // 8192 threads x 3 float4
        const float4* x4 = (const float4*)x;
        float4 v0 = x4[t * 3 + 0], v1 = x4[t * 3 + 1], v2 = x4[t * 3 + 2];
        float vv[6];
        vv[0] = v0.x + v0.w + v1.z + v2.y;
        vv[1] = v0.y + v1.x + v1.w + v2.z;
        vv[2] = v0.z + v1.y + v2.x + v2.w;
        vv[3] = v0.x*v0.x + v0.w*v0.w + v1.z*v1.z + v2.y*v2.y;
        vv[4] = v0.y*v0.y + v1.x*v1.x + v1.w*v1.w + v2.z*v2.z;
        vv[5] = v0.z*v0.z + v1.y*v1.y + v2.x*v2.x + v2.w*v2.w;
        #pragma unroll
        for (int i = 0; i < 6; ++i) {
            #pragma unroll
            for (int off = 1; off < 64; off <<= 1) vv[i] += __shfl_xor(vv[i], off);
        }
        __shared__ float part[4][6];
        if ((threadIdx.x & 63) == 0) {
            #pragma unroll
            for (int i = 0; i < 6; ++i) part[threadIdx.x >> 6][i] = vv[i];
        }
        __syncthreads();
        if (threadIdx.x < 6)
            sums[bid * 8 + threadIdx.x] = part[0][threadIdx.x] + part[1][threadIdx.x] +
                                          part[2][threadIdx.x] + part[3][threadIdx.x];
    }
}

// ---------------- fused attention layer ----------------
// grid (bx=8, a=32, nb=2); block 256 = 4 waves; wave = cg*2 + hp;
// hp = headpair (channels hp*32..+31); cg = colgroup (cells bb0+cg*2, +1).
// lane: col = lane&31 -> (ci = col>>4 cell-in-group, e = col&15 time row);
// h5 = lane>>5. Each wave: all 27 m's, softmax in registers, no merge.
template <bool FIRST>
__global__ __launch_bounds__(256, 3)
void layer_fused(const float* __restrict__ x, const float* __restrict__ sums,
                 const float* __restrict__ W_in, const float* __restrict__ b_in,
                 const short* __restrict__ hbf_in, short* __restrict__ hbf_out,
                 const float* __restrict__ Wout, const float* __restrict__ bout,
                 float* __restrict__ out,
                 const short* __restrict__ wqB, const float* __restrict__ bq,
                 const short* __restrict__ wkB, const float* __restrict__ bk,
                 const short* __restrict__ wvB, const float* __restrict__ bv) {
    __shared__ short HnS[324 * 64];   // 41.5 KB halo; reused for hf (SECOND)
    __shared__ float Waux[256];
    __shared__ float bn6[6];

    const int tid = threadIdx.x;
    const int bb0 = blockIdx.x * 4, a = blockIdx.y, nb = blockIdx.z;

    if (FIRST) {
        if (tid < 3) {
            float s = 0.f, qq = 0.f;
            #pragma unroll
            for (int p = 0; p < 32; ++p) { s += sums[p * 8 + tid]; qq += sums[p * 8 + 3 + tid]; }
            float mean = s * (1.f / 32768.f);
            float var  = qq * (1.f / 32768.f) - mean * mean;
            bn6[tid]     = mean;
            bn6[3 + tid] = rsqrtf(var + 1e-5f);
        }
        if (tid < 192) Waux[tid] = W_in[tid];
        else           Waux[tid] = b_in[tid - 192];
    } else {
        if (tid < 192)      Waux[tid] = Wout[tid];
        else if (tid < 195) Waux[tid] = bout[tid - 192];
    }
    __syncthreads();

    float mean0 = 0, mean1 = 0, mean2 = 0, rs0 = 0, rs1 = 0, rs2 = 0;
    if (FIRST) {
        mean0 = bn6[0]; mean1 = bn6[1]; mean2 = bn6[2];
        rs0 = bn6[3]; rs1 = bn6[4]; rs2 = bn6[5];
    }

    // ---- stage halo: 324 rows x 8 chunks of 8 bf16 ----
    // rowid = rw*18 + r; rw = spa*6 + jcol (3 spa x 6 jcol), r = time row
    for (int id = tid; id < 2592; id += 256) {
        int rowid = id >> 3, cc = id & 7;
        int r = rowid % 18;
        int rw = rowid / 18;
        int spa = rw / 6, jcol = rw - spa * 6;
        int aa = a + spa - 1, bb = bb0 + jcol - 1;
        int n  = nb * 16 + r - 1;
        short8_t v = {0, 0, 0, 0, 0, 0, 0, 0};
        if ((unsigned)n < 32u && (unsigned)aa < 32u && (unsigned)bb < 32u) {
            int cell = (n * 32 + aa) * 32 + bb;
            if (FIRST) {
                float xn0 = (x[cell*3+0] - mean0) * rs0;
                float xn1 = (x[cell*3+1] - mean1) * rs1;
                float xn2 = (x[cell*3+2] - mean2) * rs2;
                #pragma unroll
                for (int j = 0; j < 8; ++j) {
                    int c = cc * 8 + j;
                    float h = Waux[192+c] + xn0*Waux[c] + xn1*Waux[64+c] + xn2*Waux[128+c];
                    v[j] = f2bs(h);
                }
            } else {
                v = *(const short8_t*)&hbf_in[cell * 64 + cc * 8];
            }
        }
        *(short8_t*)&HnS[hn_idx(rowid, cc)] = v;
    }
    __syncthreads();

    const int lane = tid & 63;
    const int wv4  = tid >> 6;
    const int hp   = wv4 & 1;        // headpair
    const int cg   = wv4 >> 1;       // colgroup (2 cells)
    const int col  = lane & 31;
    const int e    = col & 15;
    const int ci   = col >> 4;
    const int h5   = lane >> 5;
    const int cell4 = cg * 2 + ci;   // cell index within block, 0..3
    const int bcell = bb0 + cell4;   // absolute b of this lane's cell

    // validity masks
    unsigned amask = 0;
    #pragma unroll
    for (int d = 0; d < 3; ++d) if ((unsigned)(a + d - 1) < 32u) amask |= 1u << d;
    unsigned vmask = 0;
    #pragma unroll
    for (int j = 0; j < 3; ++j) if ((unsigned)(bcell + j - 1) < 32u) vmask |= 1u << j;

    const int elane = cell4 * 18 + e;   // per-lane halo-row offset

    // ---- Q projection (center: spa=1 -> rw = 6 + cell4 + 1): 4 MFMAs ----
    floatx16 qv;
    {
        const float* bqp = &bq[hp * 32 + 4 * h5];
        const float4 qa = *(const float4*)&bqp[0];
        const float4 qb = *(const float4*)&bqp[8];
        const float4 qc = *(const float4*)&bqp[16];
        const float4 qd = *(const float4*)&bqp[24];
        qv = floatx16{qa.x,qa.y,qa.z,qa.w, qb.x,qb.y,qb.z,qb.w,
                      qc.x,qc.y,qc.z,qc.w, qd.x,qd.y,qd.z,qd.w};
        const int hrow = (7 + cell4) * 18 + e + 1;
        const int hb = hrow * 64, xr = hrow & 7;
        const short8_t b0 = *(const short8_t*)&HnS[hb + (((0 + h5) ^ xr) << 3)];
        const short8_t b1 = *(const short8_t*)&HnS[hb + (((2 + h5) ^ xr) << 3)];
        const short8_t b2 = *(const short8_t*)&HnS[hb + (((4 + h5) ^ xr) << 3)];
        const short8_t b3 = *(const short8_t*)&HnS[hb + (((6 + h5) ^ xr) << 3)];
        const short8_t* wqp = (const short8_t*)&wqB[(hp * 256 + lane) * 8];
        qv = __builtin_amdgcn_mfma_f32_32x32x16_bf16(wqp[0],   b0, qv, 0, 0, 0);
        qv = __builtin_amdgcn_mfma_f32_32x32x16_bf16(wqp[64],  b1, qv, 0, 0, 0);
        qv = __builtin_amdgcn_mfma_f32_32x32x16_bf16(wqp[128], b2, qv, 0, 0, 0);
        qv = __builtin_amdgcn_mfma_f32_32x32x16_bf16(wqp[192], b3, qv, 0, 0, 0);
    }

    // ---- fused K/V pass: ALL 27 m's per wave, branch-free ----
    floatx16 o = {0,0,0,0, 0,0,0,0, 0,0,0,0, 0,0,0,0};
    float ssA = 0.f, ssB = 0.f;

    const short* wkBase = wkB + hp * 2048 + lane * 8;
    const short* wvBase = wvB + hp * 2048 + lane * 8;
    const float* bkBase = bk + hp * 32 + 4 * h5;
    const float* bvBase = bv + hp * 32 + 4 * h5;

    #pragma unroll 3
    for (int m = 0; m < 27; ++m) {
        const int t  = (m * 57) >> 9;          // m/9 for m<27
        const int sp = m - 9 * t;
        const int di = (sp * 11) >> 5;         // sp/3 for sp<9
        const int dj = sp - 3 * di;

        const int hrow = di * 108 + dj * 18 + t + elane;
        const int hb = hrow * 64, xr = hrow & 7;
        const short8_t b0 = *(const short8_t*)&HnS[hb + (((0 + h5) ^ xr) << 3)];
        const short8_t b1 = *(const short8_t*)&HnS[hb + (((2 + h5) ^ xr) << 3)];
        const short8_t b2 = *(const short8_t*)&HnS[hb + (((4 + h5) ^ xr) << 3)];
        const short8_t b3 = *(const short8_t*)&HnS[hb + (((6 + h5) ^ xr) << 3)];

        // biases: global float4 (L1-resident, 27KB total shared by 12 waves)
        const float4 ka = *(const float4*)&bkBase[m * 64 + 0];
        const float4 kb = *(const float4*)&bkBase[m * 64 + 8];
        const float4 kc = *(const float4*)&bkBase[m * 64 + 16];
        const float4 kd = *(const float4*)&bkBase[m * 64 + 24];
        const float4 va0 = *(const float4*)&bvBase[m * 64 + 0];
        const float4 va1 = *(const float4*)&bvBase[m * 64 + 8];
        const float4 va2 = *(const float4*)&bvBase[m * 64 + 16];
        const float4 va3 = *(const float4*)&bvBase[m * 64 + 24];

        const short8_t wk0 = *(const short8_t*)&wkBase[m * 4096 + 0];
        const short8_t wk1 = *(const short8_t*)&wkBase[m * 4096 + 512];
        const short8_t wk2 = *(const short8_t*)&wkBase[m * 4096 + 1024];
        const short8_t wk3 = *(const short8_t*)&wkBase[m * 4096 + 1536];
        const short8_t wv0 = *(const short8_t*)&wvBase[m * 4096 + 0];
        const short8_t wv1 = *(const short8_t*)&wvBase[m * 4096 + 512];
        const short8_t wv2 = *(const short8_t*)&wvBase[m * 4096 + 1024];
        const short8_t wv3 = *(const short8_t*)&wvBase[m * 4096 + 1536];

        floatx16 kacc = floatx16{ka.x,ka.y,ka.z,ka.w, kb.x,kb.y,kb.z,kb.w,
                                 kc.x,kc.y,kc.z,kc.w, kd.x,kd.y,kd.z,kd.w};
        kacc = __builtin_amdgcn_mfma_f32_32x32x16_bf16(wk0, b0, kacc, 0, 0, 0);
        kacc = __builtin_amdgcn_mfma_f32_32x32x16_bf16(wk1, b1, kacc, 0, 0, 0);
        kacc = __builtin_amdgcn_mfma_f32_32x32x16_bf16(wk2, b2, kacc, 0, 0, 0);
        kacc = __builtin_amdgcn_mfma_f32_32x32x16_bf16(wk3, b3, kacc, 0, 0, 0);

        floatx16 vacc = floatx16{va0.x,va0.y,va0.z,va0.w, va1.x,va1.y,va1.z,va1.w,
                                 va2.x,va2.y,va2.z,va2.w, va3.x,va3.y,va3.z,va3.w};
        vacc = __builtin_amdgcn_mfma_f32_32x32x16_bf16(wv0, b0, vacc, 0, 0, 0);
        vacc = __builtin_amdgcn_mfma_f32_32x32x16_bf16(wv1, b1, vacc, 0, 0, 0);
        vacc = __builtin_amdgcn_mfma_f32_32x32x16_bf16(wv2, b2, vacc, 0, 0, 0);
        vacc = __builtin_amdgcn_mfma_f32_32x32x16_bf16(wv3, b3, vacc, 0, 0, 0);

        // score: head A = regs 0..7, head B = regs 8..15 (+ partner lane half)
        float pA = kacc[0] * qv[0];
        #pragma unroll
        for (int r = 1; r < 8; ++r) pA += kacc[r] * qv[r];
        float pB = kacc[8] * qv[8];
        #pragma unroll
        for (int r = 9; r < 16; ++r) pB += kacc[r] * qv[r];
        pA = half_sum(pA);
        pB = half_sum(pB);
        const float mf = (float)(((amask >> di) & (vmask >> dj)) & 1u);
        const float wA = __expf(pA) * mf;
        const float wB = __expf(pB) * mf;
        ssA += wA; ssB += wB;
        #pragma unroll
        for (int r = 0; r < 8; ++r)  o[r] += wA * vacc[r];
        #pragma unroll
        for (int r = 8; r < 16; ++r) o[r] += wB * vacc[r];
    }

    // ---- normalize (complete softmax: this wave saw all 27 m's) ----
    {
        const float invA = 1.0f / ssA;
        const float invB = 1.0f / ssB;
        #pragma unroll
        for (int r = 0; r < 8; ++r)  o[r] *= invA;
        #pragma unroll
        for (int r = 8; r < 16; ++r) o[r] *= invB;
    }

    // ---- epilogue ----
    const int n = nb * 16 + e;
    const int cell = (n * 32 + a) * 32 + bcell;
    if (FIRST) {
        const float xn0 = (x[cell*3+0] - mean0) * rs0;
        const float xn1 = (x[cell*3+1] - mean1) * rs1;
        const float xn2 = (x[cell*3+2] - mean2) * rs2;
        #pragma unroll
        for (int g = 0; g < 4; ++g) {
            short4 hb4; short* hbp = (short*)&hb4;
            #pragma unroll
            for (int i = 0; i < 4; ++i) {
                const int c = hp * 32 + g * 8 + 4 * h5 + i;
                const float res = Waux[192+c] + xn0*Waux[c] + xn1*Waux[64+c] + xn2*Waux[128+c];
                hbp[i] = f2bs(o[g * 4 + i] + res);
            }
            *(short4*)&hbf_out[cell * 64 + hp * 32 + g * 8 + 4 * h5] = hb4;
        }
    } else {
        __syncthreads();                   // all halo reads done; reuse LDS for hf
        float* hf = (float*)HnS;           // [64 cols][pitch 68]
        const int bcol = cell4 * 16 + e;   // 0..63
        #pragma unroll
        for (int g = 0; g < 4; ++g) {
            const short4 hb4 = *(const short4*)&hbf_in[cell * 64 + hp * 32 + g * 8 + 4 * h5];
            float4 tv = make_float4(o[g*4+0] + bs2f(hb4.x), o[g*4+1] + bs2f(hb4.y),
                                    o[g*4+2] + bs2f(hb4.z), o[g*4+3] + bs2f(hb4.w));
            *(float4*)&hf[bcol * 68 + hp * 32 + g * 8 + 4 * h5] = tv;
        }
        __syncthreads();
        // out-proj: 192 outputs (64 cols x 3 features), 64-ch dot each
        if (tid < 192) {
            const int rowglob = tid / 3, f = tid - rowglob * 3;  // rowglob = bcol
            float acc = Waux[192 + f];
            #pragma unroll 8
            for (int cc = 0; cc < 64; ++cc) acc += hf[rowglob * 68 + cc] * Waux[cc * 3 + f];
            const int cellb = bb0 + (rowglob >> 4), row = rowglob & 15;
            out[(((nb * 16 + row) * 32 + a) * 32 + cellb) * 3 + f] = acc;
        }
    }
}

extern "C" void kernel_launch(void* const* d_in, const int* in_sizes, int n_in,
                              void* d_out, int out_size, void* d_ws, size_t ws_size,
                              hipStream_t stream) {
    const float* x     = (const float*)d_in[0];
    const float* W_in  = (const float*)d_in[1];
    const float* b_in  = (const float*)d_in[2];
    const float* W_out = (const float*)d_in[3];
    const float* b_out = (const float*)d_in[4];
    const float* Wq    = (const float*)d_in[5];
    const float* bq    = (const float*)d_in[6];
    const float* Wk    = (const float*)d_in[7];
    const float* bk    = (const float*)d_in[8];
    const float* Wv    = (const float*)d_in[9];
    const float* bv    = (const float*)d_in[10];

    float* ws    = (float*)d_ws;
    float* sums  = ws;                          // 32 x 8 floats (BN partials)
    short* h1bf  = (short*)(ws + 256);          // 2M shorts (4 MB)
    short* wB    = h1bf + 2097152;              // 110 x 4096 bf16 (0.9 MB)
    float* out   = (float*)d_out;

    prep_kernel<<<142, 256, 0, stream>>>(Wq, Wk, Wv, wB, x, sums);

    const short* wq0 = wB;                const short* wq1 = wB + 4096;
    const short* wk0 = wB + 2 * 4096;     const short* wk1 = wB + (2 + 27) * 4096;
    const short* wv0 = wB + 56 * 4096;    const short* wv1 = wB + (56 + 27) * 4096;

    dim3 grid(8, 32, 2);
    layer_fused<true><<<grid, 256, 0, stream>>>(
        x, sums, W_in, b_in, nullptr, h1bf, nullptr, nullptr, nullptr,
        wq0, bq, wk0, bk, wv0, bv);
    layer_fused<false><<<grid, 256, 0, stream>>>(
        nullptr, nullptr, nullptr, nullptr, h1bf, nullptr, W_out, b_out, out,
        wq1, bq + 64, wk1, bk + 1728, wv1, bv + 1728);
}

// Round 8
// 131.372 us; speedup vs baseline: 1.0853x; 1.0853x over previous
//
#include <hip/hip_runtime.h>
#include <hip/hip_bf16.h>

// N=32 time, 32x32 grid, C=64 (H=4 x D=16), 3x3x3 offsets (M=27), 2 layers.
// R19 = R17 (no-m-split, 27-iter wave loop, softmax in regs, BiasS reverted
// from R18's global-bias regression) + bias-in-K-dim:
//  - Each weight matrix gets a 5th K-chunk holding the bias as TWO bf16
//    k-slots (hi + lo Kahan split -> ~1e-7 bias error, no absmax risk);
//    B-operand for that chunk is the constant {1,1,0...}. The accumulator
//    chain starts as mfma(w_aug, baug, 0) with C = inline-constant zero:
//    kills ~32 v_mov C-init + 8 LDS bias reads per m (R13 vs R17 proved the
//    kernel is VALU/instruction-bound, not occupancy/latency-bound).
//  - BiasS LDS deleted; Q bias folded the same way (no bq4 global load).
//  - prep packs the aug chunk; matrix stride 4096 -> 5120 shorts.

typedef short short8_t __attribute__((ext_vector_type(8)));
typedef float floatx16 __attribute__((ext_vector_type(16)));

__device__ __forceinline__ short f2bs(float f) {
    __hip_bfloat16 h = __float2bfloat16(f);
    return *reinterpret_cast<short*>(&h);
}
__device__ __forceinline__ float bs2f(short s) {
    union { unsigned u; float f; } v;
    v.u = ((unsigned)(unsigned short)s) << 16;
    return v.f;
}
// swizzled halo addressing: rowid in [0,324), 8 chunks of 8 shorts, pitch 64
__device__ __forceinline__ int hn_idx(int rowid, int chunk) {
    return rowid * 64 + ((chunk ^ (rowid & 7)) << 3);
}
// p(lane) + p(lane^32), all lanes (VALU pipe, no DS)
__device__ __forceinline__ float half_sum(float p) {
    float a = p, b = p;
    asm("v_permlane32_swap_b32 %0, %1" : "+v"(a), "+v"(b));
    return a + b;
}

// ---------------- prep: repack weights+bias-aug (coalesced) + BN sums ----------------
// blocks 0..109: one matrix each (incl. bias hi/lo aug chunk). 110..141: BN sums.
__global__ void prep_kernel(const float* __restrict__ Wq, const float* __restrict__ Wk,
                            const float* __restrict__ Wv, const float* __restrict__ bq,
                            const float* __restrict__ bk, const float* __restrict__ bv,
                            short* __restrict__ dst,
                            const float* __restrict__ x, float* __restrict__ sums) {
    if (blockIdx.x < 110) {
        __shared__ float Wf[4096];
        __shared__ float Bf[64];
        const int mat = blockIdx.x;
        const float *W, *B;
        if (mat < 2)       { W = Wq + mat * 4096;        B = bq + mat * 64; }
        else if (mat < 56) { W = Wk + (mat - 2) * 4096;  B = bk + (mat - 2) * 64; }
        else               { W = Wv + (mat - 56) * 4096; B = bv + (mat - 56) * 64; }
        const float4* W4 = (const float4*)W;
        #pragma unroll
        for (int i = 0; i < 4; ++i) {
            const int idx = threadIdx.x + i * 256;
            *(float4*)&Wf[idx * 4] = W4[idx];
        }
        if (threadIdx.x < 64) Bf[threadIdx.x] = B[threadIdx.x];
        __syncthreads();
        // entries: t2 = (hp*5+kk)*64 + lane, kk=4 is the bias aug chunk
        #pragma unroll
        for (int u = 0; u < 3; ++u) {
            const int t2 = u * 256 + threadIdx.x;
            if (t2 >= 640) break;
            const int hp = t2 / 320, rem = t2 - hp * 320;
            const int kk = rem >> 6, lane = rem & 63;
            short8_t v = {0, 0, 0, 0, 0, 0, 0, 0};
            if (kk < 4) {
                const int krow = kk * 16 + ((lane >> 5) << 3);
                const int col  = hp * 32 + (lane & 31);
                #pragma unroll
                for (int j = 0; j < 8; ++j) v[j] = f2bs(Wf[(krow + j) * 64 + col]);
            } else if ((lane >> 5) == 0) {
                const float b = Bf[hp * 32 + (lane & 31)];
                const short hi = f2bs(b);
                v[0] = hi;
                v[1] = f2bs(b - bs2f(hi));   // lo residual: hi+lo ~= b (f32)
            }
            *(short8_t*)&dst[(size_t)mat * 5120 + t2 * 8] = v;
        }
    } else {
        int bid = blockIdx.x - 110;
        int t = bid * 256 + threadIdx.x;          // 8192 threads x 3 float4
        const float4* x4 = (const float4*)x;
        float4 v0 = x4[t * 3 + 0], v1 = x4[t * 3 + 1], v2 = x4[t * 3 + 2];
        float vv[6];
        vv[0] = v0.x + v0.w + v1.z + v2.y;
        vv[1] = v0.y + v1.x + v1.w + v2.z;
        vv[2] = v0.z + v1.y + v2.x + v2.w;
        vv[3] = v0.x*v0.x + v0.w*v0.w + v1.z*v1.z + v2.y*v2.y;
        vv[4] = v0.y*v0.y + v1.x*v1.x + v1.w*v1.w + v2.z*v2.z;
        vv[5] = v0.z*v0.z + v1.y*v1.y + v2.x*v2.x + v2.w*v2.w;
        #pragma unroll
        for (int i = 0; i < 6; ++i) {
            #pragma unroll
            for (int off = 1; off < 64; off <<= 1) vv[i] += __shfl_xor(vv[i], off);
        }
        __shared__ float part[4][6];
        if ((threadIdx.x & 63) == 0) {
            #pragma unroll
            for (int i = 0; i < 6; ++i) part[threadIdx.x >> 6][i] = vv[i];
        }
        __syncthreads();
        if (threadIdx.x < 6)
            sums[bid * 8 + threadIdx.x] = part[0][threadIdx.x] + part[1][threadIdx.x] +
                                          part[2][threadIdx.x] + part[3][threadIdx.x];
    }
}

// ---------------- fused attention layer ----------------
// grid (bx=8, a=32, nb=2); block 256 = 4 waves; wave = cg*2 + hp;
// hp = headpair (channels hp*32..+31); cg = colgroup (cells bb0+cg*2, +1).
// lane: col = lane&31 -> (ci = col>>4 cell-in-group, e = col&15 time row);
// h5 = lane>>5. Each wave: all 27 m's, softmax in registers, no merge.
template <bool FIRST>
__global__ __launch_bounds__(256, 2)
void layer_fused(const float* __restrict__ x, const float* __restrict__ sums,
                 const float* __restrict__ W_in, const float* __restrict__ b_in,
                 const short* __restrict__ hbf_in, short* __restrict__ hbf_out,
                 const float* __restrict__ Wout, const float* __restrict__ bout,
                 float* __restrict__ out,
                 const short* __restrict__ wqB,
                 const short* __restrict__ wkB,
                 const short* __restrict__ wvB) {
    __shared__ short HnS[324 * 64];   // 41.5 KB halo; reused for hf (SECOND)
    __shared__ float Waux[256];
    __shared__ float bn6[6];

    const int tid = threadIdx.x;
    const int bb0 = blockIdx.x * 4, a = blockIdx.y, nb = blockIdx.z;

    if (FIRST) {
        if (tid < 3) {
            float s = 0.f, qq = 0.f;
            #pragma unroll
            for (int p = 0; p < 32; ++p) { s += sums[p * 8 + tid]; qq += sums[p * 8 + 3 + tid]; }
            float mean = s * (1.f / 32768.f);
            float var  = qq * (1.f / 32768.f) - mean * mean;
            bn6[tid]     = mean;
            bn6[3 + tid] = rsqrtf(var + 1e-5f);
        }
        if (tid < 192) Waux[tid] = W_in[tid];
        else           Waux[tid] = b_in[tid - 192];
    } else {
        if (tid < 192)      Waux[tid] = Wout[tid];
        else if (tid < 195) Waux[tid] = bout[tid - 192];
    }
    __syncthreads();

    float mean0 = 0, mean1 = 0, mean2 = 0, rs0 = 0, rs1 = 0, rs2 = 0;
    if (FIRST) {
        mean0 = bn6[0]; mean1 = bn6[1]; mean2 = bn6[2];
        rs0 = bn6[3]; rs1 = bn6[4]; rs2 = bn6[5];
    }

    // ---- stage halo: 324 rows x 8 chunks of 8 bf16 ----
    // rowid = rw*18 + r; rw = spa*6 + jcol (3 spa x 6 jcol), r = time row
    for (int id = tid; id < 2592; id += 256) {
        int rowid = id >> 3, cc = id & 7;
        int r = rowid % 18;
        int rw = rowid / 18;
        int spa = rw / 6, jcol = rw - spa * 6;
        int aa = a + spa - 1, bb = bb0 + jcol - 1;
        int n  = nb * 16 + r - 1;
        short8_t v = {0, 0, 0, 0, 0, 0, 0, 0};
        if ((unsigned)n < 32u && (unsigned)aa < 32u && (unsigned)bb < 32u) {
            int cell = (n * 32 + aa) * 32 + bb;
            if (FIRST) {
                float xn0 = (x[cell*3+0] - mean0) * rs0;
                float xn1 = (x[cell*3+1] - mean1) * rs1;
                float xn2 = (x[cell*3+2] - mean2) * rs2;
                #pragma unroll
                for (int j = 0; j < 8; ++j) {
                    int c = cc * 8 + j;
                    float h = Waux[192+c] + xn0*Waux[c] + xn1*Waux[64+c] + xn2*Waux[128+c];
                    v[j] = f2bs(h);
                }
            } else {
                v = *(const short8_t*)&hbf_in[cell * 64 + cc * 8];
            }
        }
        *(short8_t*)&HnS[hn_idx(rowid, cc)] = v;
    }
    __syncthreads();

    const int lane = tid & 63;
    const int wv4  = tid >> 6;
    const int hp   = wv4 & 1;        // headpair
    const int cg   = wv4 >> 1;       // colgroup (2 cells)
    const int col  = lane & 31;
    const int e    = col & 15;
    const int ci   = col >> 4;
    const int h5   = lane >> 5;
    const int cell4 = cg * 2 + ci;   // cell index within block, 0..3
    const int bcell = bb0 + cell4;   // absolute b of this lane's cell

    // validity masks
    unsigned amask = 0;
    #pragma unroll
    for (int d = 0; d < 3; ++d) if ((unsigned)(a + d - 1) < 32u) amask |= 1u << d;
    unsigned vmask = 0;
    #pragma unroll
    for (int j = 0; j < 3; ++j) if ((unsigned)(bcell + j - 1) < 32u) vmask |= 1u << j;

    const int elane = cell4 * 18 + e;   // per-lane halo-row offset

    // constant aug B-operand: k-slot0=1, k-slot1=1 (hi+lo bias) for h5==0 lanes
    const short one_bf = (short)0x3F80;
    short8_t baug = {0, 0, 0, 0, 0, 0, 0, 0};
    if (h5 == 0) { baug[0] = one_bf; baug[1] = one_bf; }
    const floatx16 ZERO = {0,0,0,0, 0,0,0,0, 0,0,0,0, 0,0,0,0};

    // ---- Q projection (center: spa=1 -> rw = 7 + cell4): aug + 4 MFMAs ----
    floatx16 qv;
    {
        const int hrow = (7 + cell4) * 18 + e + 1;
        const int hb = hrow * 64, xr = hrow & 7;
        const short8_t b0 = *(const short8_t*)&HnS[hb + (((0 + h5) ^ xr) << 3)];
        const short8_t b1 = *(const short8_t*)&HnS[hb + (((2 + h5) ^ xr) << 3)];
        const short8_t b2 = *(const short8_t*)&HnS[hb + (((4 + h5) ^ xr) << 3)];
        const short8_t b3 = *(const short8_t*)&HnS[hb + (((6 + h5) ^ xr) << 3)];
        const short8_t* wqp = (const short8_t*)&wqB[hp * 2560 + lane * 8];
        qv = __builtin_amdgcn_mfma_f32_32x32x16_bf16(wqp[256], baug, ZERO, 0, 0, 0);
        qv = __builtin_amdgcn_mfma_f32_32x32x16_bf16(wqp[0],   b0, qv, 0, 0, 0);
        qv = __builtin_amdgcn_mfma_f32_32x32x16_bf16(wqp[64],  b1, qv, 0, 0, 0);
        qv = __builtin_amdgcn_mfma_f32_32x32x16_bf16(wqp[128], b2, qv, 0, 0, 0);
        qv = __builtin_amdgcn_mfma_f32_32x32x16_bf16(wqp[192], b3, qv, 0, 0, 0);
    }

    // ---- fused K/V pass: ALL 27 m's per wave, branch-free ----
    floatx16 o = {0,0,0,0, 0,0,0,0, 0,0,0,0, 0,0,0,0};
    float ssA = 0.f, ssB = 0.f;

    const short* wkBase = wkB + hp * 2560 + lane * 8;
    const short* wvBase = wvB + hp * 2560 + lane * 8;

    #pragma unroll 3
    for (int m = 0; m < 27; ++m) {
        const int t  = (m * 57) >> 9;          // m/9 for m<27
        const int sp = m - 9 * t;
        const int di = (sp * 11) >> 5;         // sp/3 for sp<9
        const int dj = sp - 3 * di;

        const int hrow = di * 108 + dj * 18 + t + elane;
        const int hb = hrow * 64, xr = hrow & 7;
        const short8_t b0 = *(const short8_t*)&HnS[hb + (((0 + h5) ^ xr) << 3)];
        const short8_t b1 = *(const short8_t*)&HnS[hb + (((2 + h5) ^ xr) << 3)];
        const short8_t b2 = *(const short8_t*)&HnS[hb + (((4 + h5) ^ xr) << 3)];
        const short8_t b3 = *(const short8_t*)&HnS[hb + (((6 + h5) ^ xr) << 3)];

        const short8_t wk0 = *(const short8_t*)&wkBase[m * 5120 + 0];
        const short8_t wk1 = *(const short8_t*)&wkBase[m * 5120 + 512];
        const short8_t wk2 = *(const short8_t*)&wkBase[m * 5120 + 1024];
        const short8_t wk3 = *(const short8_t*)&wkBase[m * 5120 + 1536];
        const short8_t wk4 = *(const short8_t*)&wkBase[m * 5120 + 2048];
        const short8_t wv0 = *(const short8_t*)&wvBase[m * 5120 + 0];
        const short8_t wv1 = *(const short8_t*)&wvBase[m * 5120 + 512];
        const short8_t wv2 = *(const short8_t*)&wvBase[m * 5120 + 1024];
        const short8_t wv3 = *(const short8_t*)&wvBase[m * 5120 + 1536];
        const short8_t wv4 = *(const short8_t*)&wvBase[m * 5120 + 2048];

        // bias enters as an aug K-step with C = inline-constant 0 (no movs)
        floatx16 kacc = __builtin_amdgcn_mfma_f32_32x32x16_bf16(wk4, baug, ZERO, 0, 0, 0);
        kacc = __builtin_amdgcn_mfma_f32_32x32x16_bf16(wk0, b0, kacc, 0, 0, 0);
        kacc = __builtin_amdgcn_mfma_f32_32x32x16_bf16(wk1, b1, kacc, 0, 0, 0);
        kacc = __builtin_amdgcn_mfma_f32_32x32x16_bf16(wk2, b2, kacc, 0, 0, 0);
        kacc = __builtin_amdgcn_mfma_f32_32x32x16_bf16(wk3, b3, kacc, 0, 0, 0);

        floatx16 vacc = __builtin_amdgcn_mfma_f32_32x32x16_bf16(wv4, baug, ZERO, 0, 0, 0);
        vacc = __builtin_amdgcn_mfma_f32_32x32x16_bf16(wv0, b0, vacc, 0, 0, 0);
        vacc = __builtin_amdgcn_mfma_f32_32x32x16_bf16(wv1, b1, vacc, 0, 0, 0);
        vacc = __builtin_amdgcn_mfma_f32_32x32x16_bf16(wv2, b2, vacc, 0, 0, 0);
        vacc = __builtin_amdgcn_mfma_f32_32x32x16_bf16(wv3, b3, vacc, 0, 0, 0);

        // score: head A = regs 0..7, head B = regs 8..15 (+ partner lane half)
        float pA = kacc[0] * qv[0];
        #pragma unroll
        for (int r = 1; r < 8; ++r) pA += kacc[r] * qv[r];
        float pB = kacc[8] * qv[8];
        #pragma unroll
        for (int r = 9; r < 16; ++r) pB += kacc[r] * qv[r];
        pA = half_sum(pA);
        pB = half_sum(pB);
        const float mf = (float)(((amask >> di) & (vmask >> dj)) & 1u);
        const float wA = __expf(pA) * mf;
        const float wB = __expf(pB) * mf;
        ssA += wA; ssB += wB;
        #pragma unroll
        for (int r = 0; r < 8; ++r)  o[r] += wA * vacc[r];
        #pragma unroll
        for (int r = 8; r < 16; ++r) o[r] += wB * vacc[r];
    }

    // ---- normalize (complete softmax: this wave saw all 27 m's) ----
    {
        const float invA = 1.0f / ssA;
        const float invB = 1.0f / ssB;
        #pragma unroll
        for (int r = 0; r < 8; ++r)  o[r] *= invA;
        #pragma unroll
        for (int r = 8; r < 16; ++r) o[r] *= invB;
    }

    // ---- epilogue ----
    const int n = nb * 16 + e;
    const int cell = (n * 32 + a) * 32 + bcell;
    if (FIRST) {
        const float xn0 = (x[cell*3+0] - mean0) * rs0;
        const float xn1 = (x[cell*3+1] - mean1) * rs1;
        const float xn2 = (x[cell*3+2] - mean2) * rs2;
        #pragma unroll
        for (int g = 0; g < 4; ++g) {
            short4 hb4; short* hbp = (short*)&hb4;
            #pragma unroll
            for (int i = 0; i < 4; ++i) {
                const int c = hp * 32 + g * 8 + 4 * h5 + i;
                const float res = Waux[192+c] + xn0*Waux[c] + xn1*Waux[64+c] + xn2*Waux[128+c];
                hbp[i] = f2bs(o[g * 4 + i] + res);
            }
            *(short4*)&hbf_out[cell * 64 + hp * 32 + g * 8 + 4 * h5] = hb4;
        }
    } else {
        __syncthreads();                   // all halo reads done; reuse LDS for hf
        float* hf = (float*)HnS;           // [64 cols][pitch 68]
        const int bcol = cell4 * 16 + e;   // 0..63
        #pragma unroll
        for (int g = 0; g < 4; ++g) {
            const short4 hb4 = *(const short4*)&hbf_in[cell * 64 + hp * 32 + g * 8 + 4 * h5];
            float4 tv = make_float4(o[g*4+0] + bs2f(hb4.x), o[g*4+1] + bs2f(hb4.y),
                                    o[g*4+2] + bs2f(hb4.z), o[g*4+3] + bs2f(hb4.w));
            *(float4*)&hf[bcol * 68 + hp * 32 + g * 8 + 4 * h5] = tv;
        }
        __syncthreads();
        // out-proj: 192 outputs (64 cols x 3 features), 64-ch dot each
        if (tid < 192) {
            const int rowglob = tid / 3, f = tid - rowglob * 3;  // rowglob = bcol
            float acc = Waux[192 + f];
            #pragma unroll 8
            for (int cc = 0; cc < 64; ++cc) acc += hf[rowglob * 68 + cc] * Waux[cc * 3 + f];
            const int cellb = bb0 + (rowglob >> 4), row = rowglob & 15;
            out[(((nb * 16 + row) * 32 + a) * 32 + cellb) * 3 + f] = acc;
        }
    }
}

extern "C" void kernel_launch(void* const* d_in, const int* in_sizes, int n_in,
                              void* d_out, int out_size, void* d_ws, size_t ws_size,
                              hipStream_t stream) {
    const float* x     = (const float*)d_in[0];
    const float* W_in  = (const float*)d_in[1];
    const float* b_in  = (const float*)d_in[2];
    const float* W_out = (const float*)d_in[3];
    const float* b_out = (const float*)d_in[4];
    const float* Wq    = (const float*)d_in[5];
    const float* bq    = (const float*)d_in[6];
    const float* Wk    = (const float*)d_in[7];
    const float* bk    = (const float*)d_in[8];
    const float* Wv    = (const float*)d_in[9];
    const float* bv    = (const float*)d_in[10];

    float* ws    = (float*)d_ws;
    float* sums  = ws;                          // 32 x 8 floats (BN partials)
    short* h1bf  = (short*)(ws + 256);          // 2M shorts (4 MB)
    short* wB    = h1bf + 2097152;              // 110 x 5120 bf16 (1.1 MB)
    float* out   = (float*)d_out;

    prep_kernel<<<142, 256, 0, stream>>>(Wq, Wk, Wv, bq, bk, bv, wB, x, sums);

    const short* wq0 = wB;                const short* wq1 = wB + 5120;
    const short* wk0 = wB + 2 * 5120;     const short* wk1 = wB + (2 + 27) * 5120;
    const short* wv0 = wB + 56 * 5120;    const short* wv1 = wB + (56 + 27) * 5120;

    dim3 grid(8, 32, 2);
    layer_fused<true><<<grid, 256, 0, stream>>>(
        x, sums, W_in, b_in, nullptr, h1bf, nullptr, nullptr, nullptr,
        wq0, wk0, wv0);
    layer_fused<false><<<grid, 256, 0, stream>>>(
        nullptr, nullptr, nullptr, nullptr, h1bf, nullptr, W_out, b_out, out,
        wq1, wk1, wv1);
}